// Round 1
// baseline (2791.184 us; speedup 1.0000x reference)
//
#include <hip/hip_runtime.h>
#include <cstddef>

#define THREADS 256

// ---------------------------------------------------------------------------
// GEMM: out[N,128] = A[N,128] @ W[128,128], f32.
// W staged fully in LDS (64KB). 32 rows per block; thread = 4 rows x 4 cols.
// LDS = 64KB (W) + 16KB (X tile) = 80KB -> 2 blocks/CU.
// ---------------------------------------------------------------------------
__global__ __launch_bounds__(256, 2)
void gemm128_kernel(const float* __restrict__ A, const float* __restrict__ W,
                    float* __restrict__ out, int N) {
    __shared__ float Ws[128 * 128];
    __shared__ float Xs[32 * 128];
    const int tid = threadIdx.x;

    // Stage W: 4096 float4
    const float4* __restrict__ W4 = (const float4*)W;
    float4* Ws4 = (float4*)Ws;
#pragma unroll
    for (int i = 0; i < 16; ++i) Ws4[tid + i * 256] = W4[tid + i * 256];

    // Stage X tile: 32 rows x 128 = 1024 float4
    const int row0 = blockIdx.x * 32;
    const float4* __restrict__ A4 = (const float4*)A;
    float4* Xs4 = (float4*)Xs;
#pragma unroll
    for (int i = 0; i < 4; ++i) {
        int li = tid + i * 256;
        int r = row0 + (li >> 5);
        float4 v = {0.f, 0.f, 0.f, 0.f};
        if (r < N) v = A4[(size_t)r * 32 + (li & 31)];
        Xs4[li] = v;
    }
    __syncthreads();

    const int c4 = tid & 31;        // which float4 of the 128-wide output row
    const int rb = (tid >> 5) * 4;  // first of 4 rows this thread owns
    float4 a0 = {0.f, 0.f, 0.f, 0.f};
    float4 a1 = {0.f, 0.f, 0.f, 0.f};
    float4 a2 = {0.f, 0.f, 0.f, 0.f};
    float4 a3 = {0.f, 0.f, 0.f, 0.f};
    const float* x0p = &Xs[(rb + 0) * 128];
    const float* x1p = &Xs[(rb + 1) * 128];
    const float* x2p = &Xs[(rb + 2) * 128];
    const float* x3p = &Xs[(rb + 3) * 128];

#pragma unroll 8
    for (int k = 0; k < 128; ++k) {
        float4 wv = Ws4[k * 32 + c4];
        float x0 = x0p[k];
        float x1 = x1p[k];
        float x2 = x2p[k];
        float x3 = x3p[k];
        a0.x = fmaf(x0, wv.x, a0.x); a0.y = fmaf(x0, wv.y, a0.y);
        a0.z = fmaf(x0, wv.z, a0.z); a0.w = fmaf(x0, wv.w, a0.w);
        a1.x = fmaf(x1, wv.x, a1.x); a1.y = fmaf(x1, wv.y, a1.y);
        a1.z = fmaf(x1, wv.z, a1.z); a1.w = fmaf(x1, wv.w, a1.w);
        a2.x = fmaf(x2, wv.x, a2.x); a2.y = fmaf(x2, wv.y, a2.y);
        a2.z = fmaf(x2, wv.z, a2.z); a2.w = fmaf(x2, wv.w, a2.w);
        a3.x = fmaf(x3, wv.x, a3.x); a3.y = fmaf(x3, wv.y, a3.y);
        a3.z = fmaf(x3, wv.z, a3.z); a3.w = fmaf(x3, wv.w, a3.w);
    }

    float4* out4 = (float4*)out;
    const int r = row0 + rb;
    if (r + 3 < N) {
        out4[(size_t)(r + 0) * 32 + c4] = a0;
        out4[(size_t)(r + 1) * 32 + c4] = a1;
        out4[(size_t)(r + 2) * 32 + c4] = a2;
        out4[(size_t)(r + 3) * 32 + c4] = a3;
    } else {
        if (r + 0 < N) out4[(size_t)(r + 0) * 32 + c4] = a0;
        if (r + 1 < N) out4[(size_t)(r + 1) * 32 + c4] = a1;
        if (r + 2 < N) out4[(size_t)(r + 2) * 32 + c4] = a2;
        if (r + 3 < N) out4[(size_t)(r + 3) * 32 + c4] = a3;
    }
}

// ---------------------------------------------------------------------------
// dst = -src  (initializes the spmm accumulator so S = spmm(...) - XW)
// ---------------------------------------------------------------------------
__global__ void negcopy_kernel(const float* __restrict__ src, float* __restrict__ dst,
                               int n4) {
    int i = blockIdx.x * blockDim.x + threadIdx.x;
    if (i < n4) {
        float4 v = ((const float4*)src)[i];
        float4 o = {-v.x, -v.y, -v.z, -v.w};
        ((float4*)dst)[i] = o;
    }
}

// ---------------------------------------------------------------------------
// S[row] += 2*val * X[col]  over all edges. 32 lanes per edge, float4/lane.
// ---------------------------------------------------------------------------
__global__ void spmm_scatter_kernel(const int* __restrict__ erows,
                                    const int* __restrict__ ecols,
                                    const float* __restrict__ evals,
                                    const float* __restrict__ X,
                                    float* __restrict__ S, int E) {
    long long idx = (long long)blockIdx.x * blockDim.x + threadIdx.x;
    int e = (int)(idx >> 5);
    if (e >= E) return;
    int lane = (int)(idx & 31);
    int row = erows[e];
    int col = ecols[e];
    float v = 2.0f * evals[e];
    float4 x = ((const float4*)X)[(size_t)col * 32 + lane];
    float* s = S + (size_t)row * 128 + (size_t)lane * 4;
    atomicAdd(s + 0, v * x.x);
    atomicAdd(s + 1, v * x.y);
    atomicAdd(s + 2, v * x.z);
    atomicAdd(s + 3, v * x.w);
}

extern "C" void kernel_launch(void* const* d_in, const int* in_sizes, int n_in,
                              void* d_out, int out_size, void* d_ws, size_t ws_size,
                              hipStream_t stream) {
    const float* X     = (const float*)d_in[0];
    const int*   erows = (const int*)d_in[1];
    const int*   ecols = (const int*)d_in[2];
    const float* evals = (const float*)d_in[3];
    const float* W     = (const float*)d_in[4];
    float* out = (float*)d_out;

    const int N = in_sizes[0] / 128;  // 50000
    const int E = in_sizes[1];        // 800000

    float* ws0 = (float*)d_ws;                 // XW  (= xs[0] = xs[1])
    float* ws1 = ws0 + (size_t)N * 128;        // S accumulator

    const int gemm_blocks = (N + 31) / 32;
    const int n4 = N * 32;
    const int nc_blocks = (n4 + 255) / 256;
    const int sc_blocks = (int)(((long long)E * 32 + 255) / 256);

    // 1. XW = X @ W
    gemm128_kernel<<<gemm_blocks, THREADS, 0, stream>>>(X, W, ws0, N);
    // 2. S = -XW
    negcopy_kernel<<<nc_blocks, THREADS, 0, stream>>>(ws0, ws1, n4);
    // 3. S += spmm(2*vals, XW)
    spmm_scatter_kernel<<<sc_blocks, THREADS, 0, stream>>>(erows, ecols, evals, ws0, ws1, E);
    // 4. X2 = S @ W   (stash in d_out; overwritten at step 7)
    gemm128_kernel<<<gemm_blocks, THREADS, 0, stream>>>(ws1, W, out, N);
    // 5. S = -XW
    negcopy_kernel<<<nc_blocks, THREADS, 0, stream>>>(ws0, ws1, n4);
    // 6. S += spmm(2*vals, X2)
    spmm_scatter_kernel<<<sc_blocks, THREADS, 0, stream>>>(erows, ecols, evals, out, ws1, E);
    // 7. out = S @ W
    gemm128_kernel<<<gemm_blocks, THREADS, 0, stream>>>(ws1, W, out, N);
}

// Round 2
// 335.548 us; speedup vs baseline: 8.3183x; 8.3183x over previous
//
#include <hip/hip_runtime.h>
#include <cstddef>

#define THREADS 256

// ---------------------------------------------------------------------------
// GEMM: out[N,128] = A[N,128] @ W[128,128], f32.
// W staged fully in LDS (64KB). 32 rows per block; thread = 4 rows x 4 cols.
// ---------------------------------------------------------------------------
__global__ __launch_bounds__(256, 2)
void gemm128_kernel(const float* __restrict__ A, const float* __restrict__ W,
                    float* __restrict__ out, int N) {
    __shared__ float Ws[128 * 128];
    __shared__ float Xs[32 * 128];
    const int tid = threadIdx.x;

    const float4* __restrict__ W4 = (const float4*)W;
    float4* Ws4 = (float4*)Ws;
#pragma unroll
    for (int i = 0; i < 16; ++i) Ws4[tid + i * 256] = W4[tid + i * 256];

    const int row0 = blockIdx.x * 32;
    const float4* __restrict__ A4 = (const float4*)A;
    float4* Xs4 = (float4*)Xs;
#pragma unroll
    for (int i = 0; i < 4; ++i) {
        int li = tid + i * 256;
        int r = row0 + (li >> 5);
        float4 v = {0.f, 0.f, 0.f, 0.f};
        if (r < N) v = A4[(size_t)r * 32 + (li & 31)];
        Xs4[li] = v;
    }
    __syncthreads();

    const int c4 = tid & 31;
    const int rb = (tid >> 5) * 4;
    float4 a0 = {0.f, 0.f, 0.f, 0.f};
    float4 a1 = {0.f, 0.f, 0.f, 0.f};
    float4 a2 = {0.f, 0.f, 0.f, 0.f};
    float4 a3 = {0.f, 0.f, 0.f, 0.f};
    const float* x0p = &Xs[(rb + 0) * 128];
    const float* x1p = &Xs[(rb + 1) * 128];
    const float* x2p = &Xs[(rb + 2) * 128];
    const float* x3p = &Xs[(rb + 3) * 128];

#pragma unroll 8
    for (int k = 0; k < 128; ++k) {
        float4 wv = Ws4[k * 32 + c4];
        float x0 = x0p[k];
        float x1 = x1p[k];
        float x2 = x2p[k];
        float x3 = x3p[k];
        a0.x = fmaf(x0, wv.x, a0.x); a0.y = fmaf(x0, wv.y, a0.y);
        a0.z = fmaf(x0, wv.z, a0.z); a0.w = fmaf(x0, wv.w, a0.w);
        a1.x = fmaf(x1, wv.x, a1.x); a1.y = fmaf(x1, wv.y, a1.y);
        a1.z = fmaf(x1, wv.z, a1.z); a1.w = fmaf(x1, wv.w, a1.w);
        a2.x = fmaf(x2, wv.x, a2.x); a2.y = fmaf(x2, wv.y, a2.y);
        a2.z = fmaf(x2, wv.z, a2.z); a2.w = fmaf(x2, wv.w, a2.w);
        a3.x = fmaf(x3, wv.x, a3.x); a3.y = fmaf(x3, wv.y, a3.y);
        a3.z = fmaf(x3, wv.z, a3.z); a3.w = fmaf(x3, wv.w, a3.w);
    }

    float4* out4 = (float4*)out;
    const int r = row0 + rb;
    if (r + 3 < N) {
        out4[(size_t)(r + 0) * 32 + c4] = a0;
        out4[(size_t)(r + 1) * 32 + c4] = a1;
        out4[(size_t)(r + 2) * 32 + c4] = a2;
        out4[(size_t)(r + 3) * 32 + c4] = a3;
    } else {
        if (r + 0 < N) out4[(size_t)(r + 0) * 32 + c4] = a0;
        if (r + 1 < N) out4[(size_t)(r + 1) * 32 + c4] = a1;
        if (r + 2 < N) out4[(size_t)(r + 2) * 32 + c4] = a2;
        if (r + 3 < N) out4[(size_t)(r + 3) * 32 + c4] = a3;
    }
}

// ---------------------------------------------------------------------------
// CSR build: histogram -> scan (3 kernels) -> scatter
// ---------------------------------------------------------------------------
__global__ void hist_kernel(const int* __restrict__ erows, int* __restrict__ counts, int E) {
    int e = blockIdx.x * blockDim.x + threadIdx.x;
    if (e < E) atomicAdd(&counts[erows[e]], 1);
}

// Per-block inclusive scan of 1024-chunks (Hillis-Steele in LDS).
__global__ __launch_bounds__(1024)
void scanA_kernel(const int* __restrict__ counts, int* __restrict__ rowptr,
                  int* __restrict__ blocksum, int n) {
    __shared__ int buf[1024];
    const int tid = threadIdx.x;
    const int i = blockIdx.x * 1024 + tid;
    int v = (i < n) ? counts[i] : 0;
    buf[tid] = v;
    __syncthreads();
#pragma unroll
    for (int off = 1; off < 1024; off <<= 1) {
        int t = (tid >= off) ? buf[tid - off] : 0;
        __syncthreads();
        buf[tid] += t;
        __syncthreads();
    }
    if (i < n) rowptr[i + 1] = buf[tid];
    if (tid == 1023) blocksum[blockIdx.x] = buf[1023];
}

// Serial exclusive scan of the (few) block sums.
__global__ void scanB_kernel(int* __restrict__ blocksum, int nb) {
    if (threadIdx.x == 0 && blockIdx.x == 0) {
        int acc = 0;
        for (int b = 0; b < nb; ++b) {
            int t = blocksum[b];
            blocksum[b] = acc;
            acc += t;
        }
    }
}

// Add block offsets; produce final rowptr and a cursor copy for the scatter.
__global__ void scanC_kernel(int* __restrict__ rowptr, int* __restrict__ cursor,
                             const int* __restrict__ blocksum, int n) {
    int i = blockIdx.x * blockDim.x + threadIdx.x;
    if (i < n) {
        int v = rowptr[i + 1] + blocksum[i >> 10];
        rowptr[i + 1] = v;
        cursor[i + 1] = v;
    }
    if (i == 0) { rowptr[0] = 0; cursor[0] = 0; }
}

// Scatter edges into CSR slots: (col, 2*val) packed as int2.
__global__ void scatter_kernel(const int* __restrict__ erows, const int* __restrict__ ecols,
                               const float* __restrict__ evals, int* __restrict__ cursor,
                               int2* __restrict__ csr, int E) {
    int e = blockIdx.x * blockDim.x + threadIdx.x;
    if (e < E) {
        int r = erows[e];
        int pos = atomicAdd(&cursor[r], 1);
        int2 p;
        p.x = ecols[e];
        p.y = __float_as_int(2.0f * evals[e]);
        csr[pos] = p;
    }
}

// ---------------------------------------------------------------------------
// Gather SpMM: S[row] = sum_e 2*val_e * X[col_e]  -  XW[row]
// 32 lanes per row, float4 per lane. No atomics.
// ---------------------------------------------------------------------------
__global__ void spmm_gather_kernel(const int* __restrict__ rowptr, const int2* __restrict__ csr,
                                   const float* __restrict__ X, const float* __restrict__ XW,
                                   float* __restrict__ S, int N) {
    long long idx = (long long)blockIdx.x * blockDim.x + threadIdx.x;
    int row = (int)(idx >> 5);
    if (row >= N) return;
    int lane = (int)(idx & 31);
    const float4* __restrict__ X4 = (const float4*)X;
    float4 acc = ((const float4*)XW)[(size_t)row * 32 + lane];
    acc.x = -acc.x; acc.y = -acc.y; acc.z = -acc.z; acc.w = -acc.w;
    const int p1 = rowptr[row + 1];
    for (int p = rowptr[row]; p < p1; ++p) {
        int2 cv = csr[p];
        float v = __int_as_float(cv.y);
        float4 x = X4[(size_t)cv.x * 32 + lane];
        acc.x = fmaf(v, x.x, acc.x);
        acc.y = fmaf(v, x.y, acc.y);
        acc.z = fmaf(v, x.z, acc.z);
        acc.w = fmaf(v, x.w, acc.w);
    }
    ((float4*)S)[(size_t)row * 32 + lane] = acc;
}

extern "C" void kernel_launch(void* const* d_in, const int* in_sizes, int n_in,
                              void* d_out, int out_size, void* d_ws, size_t ws_size,
                              hipStream_t stream) {
    const float* X     = (const float*)d_in[0];
    const int*   erows = (const int*)d_in[1];
    const int*   ecols = (const int*)d_in[2];
    const float* evals = (const float*)d_in[3];
    const float* W     = (const float*)d_in[4];
    float* out = (float*)d_out;

    const int N = in_sizes[0] / 128;  // 50000
    const int E = in_sizes[1];        // 800000

    // Workspace layout (all 4-byte elems)
    float* ws0    = (float*)d_ws;                      // XW        (N*128)
    float* ws1    = ws0 + (size_t)N * 128;             // S accum   (N*128)
    int*   rowptr = (int*)(ws1 + (size_t)N * 128);     // N+1
    int*   cursor = rowptr + (N + 1);                  // N+1
    int*   counts = cursor + (N + 1);                  // N
    int*   bsum   = counts + N;                        // <=64
    int2*  csr    = (int2*)(bsum + 64);                // E int2

    const int gemm_blocks = (N + 31) / 32;
    const int e_blocks    = (E + 255) / 256;
    const int nb          = (N + 1023) / 1024;          // scanA blocks
    const int g_blocks    = (int)(((long long)N * 32 + 255) / 256);

    // --- CSR build (graph identical for both spmms) ---
    hipMemsetAsync(counts, 0, (size_t)N * sizeof(int), stream);
    hist_kernel<<<e_blocks, THREADS, 0, stream>>>(erows, counts, E);
    scanA_kernel<<<nb, 1024, 0, stream>>>(counts, rowptr, bsum, N);
    scanB_kernel<<<1, 64, 0, stream>>>(bsum, nb);
    scanC_kernel<<<(N + 255) / 256, THREADS, 0, stream>>>(rowptr, cursor, bsum, N);
    scatter_kernel<<<e_blocks, THREADS, 0, stream>>>(erows, ecols, evals, cursor, csr, E);

    // --- Chebyshev chain ---
    // 1. XW = X @ W   (= xs[0] = xs[1])
    gemm128_kernel<<<gemm_blocks, THREADS, 0, stream>>>(X, W, ws0, N);
    // 2. S = spmm(2v, XW) - XW
    spmm_gather_kernel<<<g_blocks, THREADS, 0, stream>>>(rowptr, csr, ws0, ws0, ws1, N);
    // 3. X2 = S @ W   (stash in d_out)
    gemm128_kernel<<<gemm_blocks, THREADS, 0, stream>>>(ws1, W, out, N);
    // 4. S = spmm(2v, X2) - XW
    spmm_gather_kernel<<<g_blocks, THREADS, 0, stream>>>(rowptr, csr, out, ws0, ws1, N);
    // 5. out = S @ W
    gemm128_kernel<<<gemm_blocks, THREADS, 0, stream>>>(ws1, W, out, N);
}

// Round 3
// 292.143 us; speedup vs baseline: 9.5542x; 1.1486x over previous
//
#include <hip/hip_runtime.h>
#include <cstddef>

#define THREADS 256

// ---------------------------------------------------------------------------
// GEMM: out[N,128] = A[N,128] @ W[128,128], f32. Used only for W^2, W^3.
// ---------------------------------------------------------------------------
__global__ __launch_bounds__(256, 2)
void gemm128_kernel(const float* __restrict__ A, const float* __restrict__ W,
                    float* __restrict__ out, int N) {
    __shared__ float Ws[128 * 128];
    __shared__ float Xs[32 * 128];
    const int tid = threadIdx.x;

    const float4* __restrict__ W4 = (const float4*)W;
    float4* Ws4 = (float4*)Ws;
#pragma unroll
    for (int i = 0; i < 16; ++i) Ws4[tid + i * 256] = W4[tid + i * 256];

    const int row0 = blockIdx.x * 32;
    const float4* __restrict__ A4 = (const float4*)A;
    float4* Xs4 = (float4*)Xs;
#pragma unroll
    for (int i = 0; i < 4; ++i) {
        int li = tid + i * 256;
        int r = row0 + (li >> 5);
        float4 v = {0.f, 0.f, 0.f, 0.f};
        if (r < N) v = A4[(size_t)r * 32 + (li & 31)];
        Xs4[li] = v;
    }
    __syncthreads();

    const int c4 = tid & 31;
    const int rb = (tid >> 5) * 4;
    float4 a0 = {0.f, 0.f, 0.f, 0.f};
    float4 a1 = {0.f, 0.f, 0.f, 0.f};
    float4 a2 = {0.f, 0.f, 0.f, 0.f};
    float4 a3 = {0.f, 0.f, 0.f, 0.f};
    const float* x0p = &Xs[(rb + 0) * 128];
    const float* x1p = &Xs[(rb + 1) * 128];
    const float* x2p = &Xs[(rb + 2) * 128];
    const float* x3p = &Xs[(rb + 3) * 128];

#pragma unroll 8
    for (int k = 0; k < 128; ++k) {
        float4 wv = Ws4[k * 32 + c4];
        float x0 = x0p[k];
        float x1 = x1p[k];
        float x2 = x2p[k];
        float x3 = x3p[k];
        a0.x = fmaf(x0, wv.x, a0.x); a0.y = fmaf(x0, wv.y, a0.y);
        a0.z = fmaf(x0, wv.z, a0.z); a0.w = fmaf(x0, wv.w, a0.w);
        a1.x = fmaf(x1, wv.x, a1.x); a1.y = fmaf(x1, wv.y, a1.y);
        a1.z = fmaf(x1, wv.z, a1.z); a1.w = fmaf(x1, wv.w, a1.w);
        a2.x = fmaf(x2, wv.x, a2.x); a2.y = fmaf(x2, wv.y, a2.y);
        a2.z = fmaf(x2, wv.z, a2.z); a2.w = fmaf(x2, wv.w, a2.w);
        a3.x = fmaf(x3, wv.x, a3.x); a3.y = fmaf(x3, wv.y, a3.y);
        a3.z = fmaf(x3, wv.z, a3.z); a3.w = fmaf(x3, wv.w, a3.w);
    }

    float4* out4 = (float4*)out;
    const int r = row0 + rb;
    if (r + 3 < N) {
        out4[(size_t)(r + 0) * 32 + c4] = a0;
        out4[(size_t)(r + 1) * 32 + c4] = a1;
        out4[(size_t)(r + 2) * 32 + c4] = a2;
        out4[(size_t)(r + 3) * 32 + c4] = a3;
    } else {
        if (r + 0 < N) out4[(size_t)(r + 0) * 32 + c4] = a0;
        if (r + 1 < N) out4[(size_t)(r + 1) * 32 + c4] = a1;
        if (r + 2 < N) out4[(size_t)(r + 2) * 32 + c4] = a2;
        if (r + 3 < N) out4[(size_t)(r + 3) * 32 + c4] = a3;
    }
}

// ---------------------------------------------------------------------------
// Dual GEMM: out = A1 @ Wa  -  A2 @ Wb   (all [*,128]x[128,128], f32)
// Two passes sharing one LDS W buffer (restaged); Wb negated during staging.
// Inner loop: float4 X reads (k-chunks of 4) -> 8 b128 LDS reads / 64 FMA.
// ---------------------------------------------------------------------------
__device__ __forceinline__ void rowfma(float4& acc, const float4 xv,
                                       const float4 w0, const float4 w1,
                                       const float4 w2, const float4 w3) {
    acc.x = fmaf(xv.x, w0.x, acc.x); acc.y = fmaf(xv.x, w0.y, acc.y);
    acc.z = fmaf(xv.x, w0.z, acc.z); acc.w = fmaf(xv.x, w0.w, acc.w);
    acc.x = fmaf(xv.y, w1.x, acc.x); acc.y = fmaf(xv.y, w1.y, acc.y);
    acc.z = fmaf(xv.y, w1.z, acc.z); acc.w = fmaf(xv.y, w1.w, acc.w);
    acc.x = fmaf(xv.z, w2.x, acc.x); acc.y = fmaf(xv.z, w2.y, acc.y);
    acc.z = fmaf(xv.z, w2.z, acc.z); acc.w = fmaf(xv.z, w2.w, acc.w);
    acc.x = fmaf(xv.w, w3.x, acc.x); acc.y = fmaf(xv.w, w3.y, acc.y);
    acc.z = fmaf(xv.w, w3.z, acc.z); acc.w = fmaf(xv.w, w3.w, acc.w);
}

__global__ __launch_bounds__(256, 2)
void gemm_dual_kernel(const float* __restrict__ A1, const float* __restrict__ Wa,
                      const float* __restrict__ A2, const float* __restrict__ Wb,
                      float* __restrict__ out, int N) {
    __shared__ float Ws[128 * 128];
    __shared__ float Xs[32 * 128];
    const int tid = threadIdx.x;
    const int row0 = blockIdx.x * 32;
    const int c4 = tid & 31;
    const int rb = (tid >> 5) * 4;

    float4 a0 = {0.f, 0.f, 0.f, 0.f};
    float4 a1 = {0.f, 0.f, 0.f, 0.f};
    float4 a2 = {0.f, 0.f, 0.f, 0.f};
    float4 a3 = {0.f, 0.f, 0.f, 0.f};
    float4* Ws4 = (float4*)Ws;
    float4* Xs4 = (float4*)Xs;

    for (int pass = 0; pass < 2; ++pass) {
        const float4* __restrict__ Wsrc = (const float4*)(pass ? Wb : Wa);
        const float4* __restrict__ Asrc = (const float4*)(pass ? A2 : A1);
        if (pass) __syncthreads();  // loop-1 readers done before restage
#pragma unroll
        for (int i = 0; i < 16; ++i) {
            float4 v = Wsrc[tid + i * 256];
            if (pass) { v.x = -v.x; v.y = -v.y; v.z = -v.z; v.w = -v.w; }
            Ws4[tid + i * 256] = v;
        }
#pragma unroll
        for (int i = 0; i < 4; ++i) {
            int li = tid + i * 256;
            int r = row0 + (li >> 5);
            float4 v = {0.f, 0.f, 0.f, 0.f};
            if (r < N) v = Asrc[(size_t)r * 32 + (li & 31)];
            Xs4[li] = v;
        }
        __syncthreads();

#pragma unroll 4
        for (int kq = 0; kq < 32; ++kq) {
            float4 w0 = Ws4[(4 * kq + 0) * 32 + c4];
            float4 w1 = Ws4[(4 * kq + 1) * 32 + c4];
            float4 w2 = Ws4[(4 * kq + 2) * 32 + c4];
            float4 w3 = Ws4[(4 * kq + 3) * 32 + c4];
            float4 xv0 = Xs4[(rb + 0) * 32 + kq];
            float4 xv1 = Xs4[(rb + 1) * 32 + kq];
            float4 xv2 = Xs4[(rb + 2) * 32 + kq];
            float4 xv3 = Xs4[(rb + 3) * 32 + kq];
            rowfma(a0, xv0, w0, w1, w2, w3);
            rowfma(a1, xv1, w0, w1, w2, w3);
            rowfma(a2, xv2, w0, w1, w2, w3);
            rowfma(a3, xv3, w0, w1, w2, w3);
        }
    }

    float4* out4 = (float4*)out;
    const int r = row0 + rb;
    if (r + 3 < N) {
        out4[(size_t)(r + 0) * 32 + c4] = a0;
        out4[(size_t)(r + 1) * 32 + c4] = a1;
        out4[(size_t)(r + 2) * 32 + c4] = a2;
        out4[(size_t)(r + 3) * 32 + c4] = a3;
    } else {
        if (r + 0 < N) out4[(size_t)(r + 0) * 32 + c4] = a0;
        if (r + 1 < N) out4[(size_t)(r + 1) * 32 + c4] = a1;
        if (r + 2 < N) out4[(size_t)(r + 2) * 32 + c4] = a2;
        if (r + 3 < N) out4[(size_t)(r + 3) * 32 + c4] = a3;
    }
}

// ---------------------------------------------------------------------------
// CSR build: histogram -> scan (3 kernels) -> scatter
// ---------------------------------------------------------------------------
__global__ void hist_kernel(const int* __restrict__ erows, int* __restrict__ counts, int E) {
    int e = blockIdx.x * blockDim.x + threadIdx.x;
    if (e < E) atomicAdd(&counts[erows[e]], 1);
}

__global__ __launch_bounds__(1024)
void scanA_kernel(const int* __restrict__ counts, int* __restrict__ rowptr,
                  int* __restrict__ blocksum, int n) {
    __shared__ int buf[1024];
    const int tid = threadIdx.x;
    const int i = blockIdx.x * 1024 + tid;
    int v = (i < n) ? counts[i] : 0;
    buf[tid] = v;
    __syncthreads();
#pragma unroll
    for (int off = 1; off < 1024; off <<= 1) {
        int t = (tid >= off) ? buf[tid - off] : 0;
        __syncthreads();
        buf[tid] += t;
        __syncthreads();
    }
    if (i < n) rowptr[i + 1] = buf[tid];
    if (tid == 1023) blocksum[blockIdx.x] = buf[1023];
}

// Single-wave exclusive scan of block sums (nb <= 64).
__global__ void scanB_kernel(int* __restrict__ blocksum, int nb) {
    int tid = threadIdx.x;  // 64 threads
    int orig = (tid < nb) ? blocksum[tid] : 0;
    int v = orig;
#pragma unroll
    for (int off = 1; off < 64; off <<= 1) {
        int t = __shfl_up(v, off);
        if (tid >= off) v += t;
    }
    if (tid < nb) blocksum[tid] = v - orig;  // exclusive
}

__global__ void scanC_kernel(int* __restrict__ rowptr, int* __restrict__ cursor,
                             const int* __restrict__ blocksum, int n) {
    int i = blockIdx.x * blockDim.x + threadIdx.x;
    if (i < n) {
        int v = rowptr[i + 1] + blocksum[i >> 10];
        rowptr[i + 1] = v;
        cursor[i + 1] = v;
    }
    if (i == 0) { rowptr[0] = 0; cursor[0] = 0; }
}

__global__ void scatter_kernel(const int* __restrict__ erows, const int* __restrict__ ecols,
                               const float* __restrict__ evals, int* __restrict__ cursor,
                               int2* __restrict__ csr, int E) {
    int e = blockIdx.x * blockDim.x + threadIdx.x;
    if (e < E) {
        int r = erows[e];
        int pos = atomicAdd(&cursor[r], 1);
        int2 p;
        p.x = ecols[e];
        p.y = __float_as_int(2.0f * evals[e]);
        csr[pos] = p;
    }
}

// ---------------------------------------------------------------------------
// Gather SpMM: S[row] = sum_e 2*val_e * X[col_e]  (-  init[row] if init)
// 32 lanes per row, float4 per lane, 4-edge unrolled for MLP. No atomics.
// ---------------------------------------------------------------------------
__global__ void spmm_gather_kernel(const int* __restrict__ rowptr, const int2* __restrict__ csr,
                                   const float* __restrict__ X, const float* __restrict__ init,
                                   float* __restrict__ S, int N) {
    long long idx = (long long)blockIdx.x * blockDim.x + threadIdx.x;
    int row = (int)(idx >> 5);
    if (row >= N) return;
    int lane = (int)(idx & 31);
    const float4* __restrict__ X4 = (const float4*)X;
    float4 acc = {0.f, 0.f, 0.f, 0.f};
    if (init) {
        float4 t = ((const float4*)init)[(size_t)row * 32 + lane];
        acc.x = -t.x; acc.y = -t.y; acc.z = -t.z; acc.w = -t.w;
    }
    int p = rowptr[row];
    const int p1 = rowptr[row + 1];
    for (; p + 3 < p1; p += 4) {
        int2 cv0 = csr[p + 0];
        int2 cv1 = csr[p + 1];
        int2 cv2 = csr[p + 2];
        int2 cv3 = csr[p + 3];
        float4 x0 = X4[(size_t)cv0.x * 32 + lane];
        float4 x1 = X4[(size_t)cv1.x * 32 + lane];
        float4 x2 = X4[(size_t)cv2.x * 32 + lane];
        float4 x3 = X4[(size_t)cv3.x * 32 + lane];
        float v0 = __int_as_float(cv0.y);
        float v1 = __int_as_float(cv1.y);
        float v2 = __int_as_float(cv2.y);
        float v3 = __int_as_float(cv3.y);
        acc.x = fmaf(v0, x0.x, acc.x); acc.y = fmaf(v0, x0.y, acc.y);
        acc.z = fmaf(v0, x0.z, acc.z); acc.w = fmaf(v0, x0.w, acc.w);
        acc.x = fmaf(v1, x1.x, acc.x); acc.y = fmaf(v1, x1.y, acc.y);
        acc.z = fmaf(v1, x1.z, acc.z); acc.w = fmaf(v1, x1.w, acc.w);
        acc.x = fmaf(v2, x2.x, acc.x); acc.y = fmaf(v2, x2.y, acc.y);
        acc.z = fmaf(v2, x2.z, acc.z); acc.w = fmaf(v2, x2.w, acc.w);
        acc.x = fmaf(v3, x3.x, acc.x); acc.y = fmaf(v3, x3.y, acc.y);
        acc.z = fmaf(v3, x3.z, acc.z); acc.w = fmaf(v3, x3.w, acc.w);
    }
    for (; p < p1; ++p) {
        int2 cv = csr[p];
        float v = __int_as_float(cv.y);
        float4 x = X4[(size_t)cv.x * 32 + lane];
        acc.x = fmaf(v, x.x, acc.x);
        acc.y = fmaf(v, x.y, acc.y);
        acc.z = fmaf(v, x.z, acc.z);
        acc.w = fmaf(v, x.w, acc.w);
    }
    ((float4*)S)[(size_t)row * 32 + lane] = acc;
}

extern "C" void kernel_launch(void* const* d_in, const int* in_sizes, int n_in,
                              void* d_out, int out_size, void* d_ws, size_t ws_size,
                              hipStream_t stream) {
    const float* X     = (const float*)d_in[0];
    const int*   erows = (const int*)d_in[1];
    const int*   ecols = (const int*)d_in[2];
    const float* evals = (const float*)d_in[3];
    const float* W     = (const float*)d_in[4];
    float* out = (float*)d_out;

    const int N = in_sizes[0] / 128;  // 50000
    const int E = in_sizes[1];        // 800000

    // Workspace layout (4-byte elems; csr kept 8B-aligned)
    float* t2     = (float*)d_ws;                      // T2 = 2A.X - X   (N*128)
    float* u2     = t2 + (size_t)N * 128;              // U2 = 2A.T2      (N*128)
    float* W2     = u2 + (size_t)N * 128;              // 128*128
    float* W3     = W2 + 16384;                        // 128*128
    int2*  csr    = (int2*)(W3 + 16384);               // E int2 (8B-aligned)
    int*   rowptr = (int*)(csr + E);                   // N+1
    int*   cursor = rowptr + (N + 1);                  // N+1
    int*   counts = cursor + (N + 1);                  // N
    int*   bsum   = counts + N;                        // <=64

    const int gemm_blocks = (N + 31) / 32;
    const int e_blocks    = (E + 255) / 256;
    const int nb          = (N + 1023) / 1024;
    const int g_blocks    = (int)(((long long)N * 32 + 255) / 256);

    // --- W powers (independent of CSR/spmm) ---
    gemm128_kernel<<<4, THREADS, 0, stream>>>(W, W, W2, 128);   // W2 = W@W
    gemm128_kernel<<<4, THREADS, 0, stream>>>(W2, W, W3, 128);  // W3 = W2@W

    // --- CSR build ---
    hipMemsetAsync(counts, 0, (size_t)N * sizeof(int), stream);
    hist_kernel<<<e_blocks, THREADS, 0, stream>>>(erows, counts, E);
    scanA_kernel<<<nb, 1024, 0, stream>>>(counts, rowptr, bsum, N);
    scanB_kernel<<<1, 64, 0, stream>>>(bsum, nb);
    scanC_kernel<<<(N + 255) / 256, THREADS, 0, stream>>>(rowptr, cursor, bsum, N);
    scatter_kernel<<<e_blocks, THREADS, 0, stream>>>(erows, ecols, evals, cursor, csr, E);

    // --- Chebyshev chain (reassociated) ---
    // T2 = 2A.X - X
    spmm_gather_kernel<<<g_blocks, THREADS, 0, stream>>>(rowptr, csr, X, X, t2, N);
    // U2 = 2A.T2
    spmm_gather_kernel<<<g_blocks, THREADS, 0, stream>>>(rowptr, csr, t2, nullptr, u2, N);
    // out = U2@W3 - X@W2
    gemm_dual_kernel<<<gemm_blocks, THREADS, 0, stream>>>(u2, W3, X, W2, out, N);
}